// Round 11
// baseline (3675.808 us; speedup 1.0000x reference)
//
#include <hip/hip_runtime.h>

typedef unsigned short u16;
typedef unsigned int u32;
typedef __attribute__((ext_vector_type(8))) __bf16 bf16x8;
typedef __attribute__((ext_vector_type(4))) float f32x4;
typedef __attribute__((ext_vector_type(4))) u32 u32x4;

#define ASYNC16(g, l) __builtin_amdgcn_global_load_lds( \
    (const __attribute__((address_space(1))) unsigned int*)(g), \
    (__attribute__((address_space(3))) unsigned int*)(l), 16, 0, 0)

__device__ __forceinline__ u16 f2bf(float f){
  unsigned u = __float_as_uint(f);
  unsigned r = u + 0x7fffu + ((u >> 16) & 1u);
  return (u16)(r >> 16);
}

// ---------------- fp32 -> bf16 conversion ----------------
__global__ __launch_bounds__(256) void f2bf_kernel(const float* __restrict__ in,
                                                   u16* __restrict__ out, int n){
  int i = (blockIdx.x * 256 + threadIdx.x) * 8;
  if (i >= n) return;
  float4 a = *(const float4*)&in[i];
  float4 b = *(const float4*)&in[i + 4];
  u16 r[8] = {f2bf(a.x), f2bf(a.y), f2bf(a.z), f2bf(a.w),
              f2bf(b.x), f2bf(b.y), f2bf(b.z), f2bf(b.w)};
  *(uint4*)&out[i] = *(const uint4*)r;
}

// ---------------- ctx projections: ses_inf, h0 ----------------
__global__ __launch_bounds__(256) void ctx_kernel(const float* __restrict__ ctx,
    const float* __restrict__ Wses, const float* __restrict__ Ws2d,
    const float* __restrict__ bs2d, float* __restrict__ sesinf,
    float* __restrict__ h0f, u16* __restrict__ h0bf){
  int id = blockIdx.x * 4 + (threadIdx.x >> 6);
  int lane = threadIdx.x & 63;
  int n = id & 1023, b = (id >> 10) & 15, mat = id >> 14;
  const float* w = (mat ? Ws2d : Wses) + (size_t)n * 1024;
  const float* x = ctx + (size_t)b * 1024;
  float v = 0.f;
  #pragma unroll 4
  for (int k = lane; k < 1024; k += 64) v += x[k] * w[k];
  #pragma unroll
  for (int off = 32; off; off >>= 1) v += __shfl_down(v, off);
  if (lane == 0){
    if (mat == 0) sesinf[b * 1024 + n] = v;
    else {
      float t = tanhf(v + bs2d[n]);
      h0f[b * 1024 + n] = t;
      h0bf[b * 1024 + n] = f2bf(t);
    }
  }
}

// ---------------- embedding gather (bf16 rows) ----------------
__global__ void gather_kernel(const int* __restrict__ target,
                              const u16* __restrict__ embedBF, u16* __restrict__ embBF){
  int i = blockIdx.x;
  int t = target[i];
  int lane = threadIdx.x;
  *(uint4*)&embBF[(size_t)i * 512 + lane * 8] =
      *(const uint4*)&embedBF[(size_t)t * 512 + lane * 8];
}

// ---------------- bf16 GEMM: C[M][N] = A[M][K] * B[N][K]^T (+epilogue) ----------------
// SWZ: bijective XCD-aware wgid remap (requires nwg % 8 == 0)
// EPI: 0=none, 1=+bias[col], 2=+add0+add1 -> C, 3=+add0+add1 -> pairwise-max -> bf16 mxout
template<int EPI, int SWZ>
__global__ __launch_bounds__(256) void gemm_bt(
    const u16* __restrict__ A, const u16* __restrict__ B, float* __restrict__ C,
    int M, int N, int K,
    const float* __restrict__ bias, const float* __restrict__ add0,
    const float* __restrict__ add1, u16* __restrict__ mxout)
{
  __shared__ u16 sA[2][128 * 32];
  __shared__ u16 sB[2][128 * 32];
  int bx = blockIdx.x, by = blockIdx.y;
  if (SWZ){
    int nwg = gridDim.x * gridDim.y;
    int wg = by * gridDim.x + bx;
    int q = nwg >> 3;
    int nw = (wg & 7) * q + (wg >> 3);
    bx = nw % gridDim.x; by = nw / gridDim.x;
  }
  const int n0 = bx * 128;
  const int m0 = by * 128;
  const int tid = threadIdx.x;
  const int lane = tid & 63;
  const int wid = tid >> 6;
  const int wm = (wid >> 1) * 64, wn = (wid & 1) * 64;
  const int l15 = lane & 15, kg = (lane >> 4) * 8;
  (void)M;

  f32x4 zero = {0.f, 0.f, 0.f, 0.f};
  f32x4 acc[4][4];
  #pragma unroll
  for (int m = 0; m < 4; m++)
    #pragma unroll
    for (int n = 0; n < 4; n++) acc[m][n] = zero;

  auto stage = [&](int buf, int kk){
    const u16* Ab = A + (size_t)m0 * K + kk;
    const u16* Bb = B + (size_t)n0 * K + kk;
    #pragma unroll
    for (int j = 0; j < 2; j++){
      int c = j * 256 + tid;
      ASYNC16(Ab + (size_t)(c >> 2) * K + (c & 3) * 8, &sA[buf][c * 8]);
    }
    #pragma unroll
    for (int j = 0; j < 2; j++){
      int c = j * 256 + tid;
      ASYNC16(Bb + (size_t)(c >> 2) * K + (c & 3) * 8, &sB[buf][c * 8]);
    }
  };

  stage(0, 0);
  int cur = 0;
  for (int kk = 0; kk < K; kk += 32){
    __syncthreads();
    if (kk + 32 < K) stage(cur ^ 1, kk + 32);
    bf16x8 af[4], bf_[4];
    #pragma unroll
    for (int m = 0; m < 4; m++)
      af[m] = *(const bf16x8*)&sA[cur][(wm + m * 16 + l15) * 32 + kg];
    #pragma unroll
    for (int n = 0; n < 4; n++)
      bf_[n] = *(const bf16x8*)&sB[cur][(wn + n * 16 + l15) * 32 + kg];
    #pragma unroll
    for (int m = 0; m < 4; m++)
      #pragma unroll
      for (int n = 0; n < 4; n++)
        acc[m][n] = __builtin_amdgcn_mfma_f32_16x16x32_bf16(af[m], bf_[n], acc[m][n], 0, 0, 0);
    cur ^= 1;
  }

  const int rb = m0 + wm + (lane >> 4) * 4;
  const int cb = n0 + wn + l15;
  #pragma unroll
  for (int m = 0; m < 4; m++){
    #pragma unroll
    for (int n = 0; n < 4; n++){
      #pragma unroll
      for (int i = 0; i < 4; i++){
        int row = rb + m * 16 + i;
        int col = cb + n * 16;
        float v = acc[m][n][i];
        if (EPI == 1) v += bias[col];
        if (EPI == 2 || EPI == 3)
          v += add0[(row >> 8) * N + col] + add1[(size_t)row * N + col];
        if (EPI == 3){
          // pairwise maxout: col pairs (2e,2e+1) live in adjacent lanes
          float w = __shfl_xor(v, 1);
          if ((l15 & 1) == 0)
            mxout[(size_t)row * (N >> 1) + (col >> 1)] = f2bf(fmaxf(v, w));
        } else {
          C[(size_t)row * N + col] = v;
        }
      }
    }
  }
}

// ---------------- persistent GRU (16 WGs x 1024 thr, W_hh from L2) ----------------
// R4's PROVEN protocol (sc1 write-through publish -> vmcnt(0) drain -> per-WG
// flag line -> lane-per-flag poll -> sc1 bulk re-stage), with participants
// reduced 64 -> 16. WG g owns hidden cols [g*64, (g+1)*64); W_hh slice
// (384 KB) is NOT in LDS -- it is re-read each step as direct MFMA B-fragments
// from global (L2-resident: 2 WGs/XCD x 384 KB << 4 MiB, ~6 MB/step from L2,
// pipelined under the MFMA chain). LDS (static, 49 KB): staged h + gbuf + hown.
// 12 compute waves, one 16x16 output tile each (gate=wid>>2, colblk=wid&3);
// no cross-wave partial sums. Gates phase: wave = batch, lane = own col.
#define GRU_NWG 16

__global__ __launch_bounds__(1024) void gru_kernel(
    const u16* __restrict__ WhhBF, const float* __restrict__ bhh,
    const float* __restrict__ xproj, const float* __restrict__ h0f,
    const u16* __restrict__ h0bf, u16* __restrict__ hsBF, int* flags)
{
  __shared__ u16   hb[16 * 1032];       // staged h_{s-1} [batch][col], pad 8
  __shared__ float gbuf[12 * 256];      // tile t: [batch*16 + tilecol]
  __shared__ float hown[16 * 64];       // own fp32 h slice [batch][owncol]

  const int g = blockIdx.x;
  const int j0 = g * 64;
  const int tid = threadIdx.x;
  const int lane = tid & 63;
  const int wid = tid >> 6;
  const int bb = wid;                   // gates mapping: wave = batch
  const int jj = lane;                  // gates mapping: lane = own col
  const int l15 = lane & 15, kh = lane >> 4;

  hown[bb * 64 + jj] = h0f[bb * 1024 + j0 + jj];
  const float bh0 = bhh[j0 + jj];
  const float bh1 = bhh[1024 + j0 + jj];
  const float bh2 = bhh[2048 + j0 + jj];
  // compute wave's W_hh row block: rows [wid*16, wid*16+16) of the 192
  // (gate = wid>>2, own-col block = (wid&3)*16)
  const u16* wr = WhhBF +
      (size_t)((wid >> 2) * 1024 + j0 + (wid & 3) * 16 + l15) * 1024;
  u32* hs32 = (u32*)hsBF;
  __syncthreads();

  for (int s = 0; s < 256; ++s){
    // ---- stage h_{s-1} into LDS: 1024 thr x 2 dwordx4 (32 KB) ----
    if (s == 0){
      #pragma unroll
      for (int k = 0; k < 2; k++){
        int c = tid + k * 1024;
        int b = c >> 7, cg = (c & 127) * 8;
        *(uint4*)&hb[b * 1032 + cg] = *(const uint4*)&h0bf[b * 1024 + cg];
      }
    } else {
      u32x4 r[2];
      #pragma unroll
      for (int k = 0; k < 2; k++){
        int c = tid + k * 1024;
        int b = c >> 7, cg = (c & 127) * 8;
        const u16* src = &hsBF[(size_t)((b << 8) + s - 1) * 1024 + cg];
        asm volatile("global_load_dwordx4 %0, %1, off sc1"
                     : "=v"(r[k]) : "v"(src) : "memory");
      }
      asm volatile("s_waitcnt vmcnt(0)" ::: "memory");
      __builtin_amdgcn_sched_barrier(0);   // rule#18 hygiene
      #pragma unroll
      for (int k = 0; k < 2; k++){
        int c = tid + k * 1024;
        int b = c >> 7, cg = (c & 127) * 8;
        *(u32x4*)&hb[b * 1032 + cg] = r[k];
      }
    }

    // prefetch this step's x_proj scalars (consumed only in gates phase)
    const float* xp = xproj + ((size_t)(bb << 8) + s) * 3072;
    float xr = xp[j0 + jj], xz = xp[1024 + j0 + jj], xn = xp[2048 + j0 + jj];
    __syncthreads();

    // ---- MFMA: waves 0..11, one 16x16 tile each; W streamed from L2 ----
    if (wid < 12){
      f32x4 acc0 = {0.f, 0.f, 0.f, 0.f};
      f32x4 acc1 = {0.f, 0.f, 0.f, 0.f};
      const int kh8 = kh * 8;
      const u16* hrow = &hb[l15 * 1032];
      #pragma unroll 4
      for (int kk = 0; kk < 1024; kk += 64){
        bf16x8 a0 = *(const bf16x8*)&hrow[kk + kh8];
        bf16x8 w0 = *(const bf16x8*)&wr[kk + kh8];
        acc0 = __builtin_amdgcn_mfma_f32_16x16x32_bf16(a0, w0, acc0, 0, 0, 0);
        bf16x8 a1 = *(const bf16x8*)&hrow[kk + 32 + kh8];
        bf16x8 w1 = *(const bf16x8*)&wr[kk + 32 + kh8];
        acc1 = __builtin_amdgcn_mfma_f32_16x16x32_bf16(a1, w1, acc1, 0, 0, 0);
      }
      #pragma unroll
      for (int i = 0; i < 4; ++i)
        gbuf[wid * 256 + (kh * 4 + i) * 16 + l15] = acc0[i] + acc1[i];
    }
    __syncthreads();

    // ---- gates: thread (batch=bb, owncol=jj); publish sc1 packed pairs ----
    {
      int tc = (jj >> 4);                 // tile within gate
      int ic = bb * 16 + (jj & 15);       // [batch][tilecol]
      float hr = gbuf[(0 * 4 + tc) * 256 + ic] + bh0;
      float hz = gbuf[(1 * 4 + tc) * 256 + ic] + bh1;
      float hn = gbuf[(2 * 4 + tc) * 256 + ic] + bh2;
      float r = 1.f / (1.f + __expf(-(xr + hr)));
      float z = 1.f / (1.f + __expf(-(xz + hz)));
      float nn = tanhf(xn + r * hn);
      float hnew = (1.f - z) * nn + z * hown[bb * 64 + jj];
      hown[bb * 64 + jj] = hnew;
      float hnext = __shfl_down(hnew, 1);
      if ((jj & 1) == 0){
        u32 pack = (u32)f2bf(hnew) | ((u32)f2bf(hnext) << 16);
        size_t e = (size_t)((bb << 8) + s) * 1024 + j0 + jj;
        __hip_atomic_store(&hs32[e >> 1], pack, __ATOMIC_RELAXED,
                           __HIP_MEMORY_SCOPE_AGENT);
      }
    }

    if (s < 255){
      asm volatile("s_waitcnt vmcnt(0)" ::: "memory");
      __syncthreads();
      if (tid == 0)
        __hip_atomic_store(&flags[g * 32], s + 1, __ATOMIC_RELAXED,
                           __HIP_MEMORY_SCOPE_AGENT);
      if (wid == 0 && lane < GRU_NWG){
        while (__hip_atomic_load(&flags[lane * 32], __ATOMIC_RELAXED,
                                 __HIP_MEMORY_SCOPE_AGENT) <= s)
          __builtin_amdgcn_s_sleep(1);
      }
      __syncthreads();
    }
  }
}

extern "C" void kernel_launch(void* const* d_in, const int* in_sizes, int n_in,
                              void* d_out, int out_size, void* d_ws, size_t ws_size,
                              hipStream_t stream)
{
  const float* ctx    = (const float*)d_in[0];
  const int*   target = (const int*)d_in[1];
  const float* embed  = (const float*)d_in[2];
  const float* Ws2d   = (const float*)d_in[3];
  const float* bs2d   = (const float*)d_in[4];
  const float* Wdec   = (const float*)d_in[5];
  const float* Wses   = (const float*)d_in[6];
  const float* Wemb   = (const float*)d_in[7];
  const float* bemb   = (const float*)d_in[8];
  const float* Wih    = (const float*)d_in[9];
  const float* Whh    = (const float*)d_in[10];
  const float* bih    = (const float*)d_in[11];
  const float* bhh    = (const float*)d_in[12];
  float* out = (float*)d_out;

  char* ws = (char*)d_ws;
  size_t off = 0;
  auto alloc = [&](size_t bytes)->char*{
    char* p = ws + off; off += (bytes + 255) & ~(size_t)255; return p;
  };
  u16*   embedBF = (u16*)alloc(32000ull * 512 * 2);
  u16*   WihBF   = (u16*)alloc(3072ull * 512 * 2);
  u16*   WembBF  = (u16*)alloc(1024ull * 512 * 2);
  u16*   WdecBF  = (u16*)alloc(1024ull * 1024 * 2);
  u16*   WhhBF   = (u16*)alloc(3072ull * 1024 * 2);
  u16*   embBF   = (u16*)alloc(4096ull * 512 * 2);
  float* xproj   = (float*)alloc(4096ull * 3072 * 4);
  float* embinf  = (float*)alloc(4096ull * 1024 * 4);
  float* sesinf  = (float*)alloc(16ull * 1024 * 4);
  float* h0f     = (float*)alloc(16ull * 1024 * 4);
  u16*   h0bf    = (u16*)alloc(16ull * 1024 * 2);
  u16*   hsBF    = (u16*)alloc(4096ull * 1024 * 2);
  u16*   mxBF    = (u16*)alloc(4096ull * 512 * 2);
  int*   flags   = (int*)alloc(16384);
  (void)ws_size; (void)in_sizes; (void)n_in; (void)out_size;

  hipMemsetAsync(flags, 0, 16384, stream);

  auto conv = [&](const float* in, u16* o, size_t n){
    f2bf_kernel<<<dim3((unsigned)((n / 8 + 255) / 256)), 256, 0, stream>>>(in, o, (int)n);
  };
  conv(embed, embedBF, 32000ull * 512);
  conv(Wih,   WihBF,   3072ull * 512);
  conv(Wemb,  WembBF,  1024ull * 512);
  conv(Wdec,  WdecBF,  1024ull * 1024);
  conv(Whh,   WhhBF,   3072ull * 1024);

  ctx_kernel<<<8192, 256, 0, stream>>>(ctx, Wses, Ws2d, bs2d, sesinf, h0f, h0bf);
  gather_kernel<<<4096, 64, 0, stream>>>(target, embedBF, embBF);

  // x_proj = emb @ W_ih^T + b_ih ; emb_inf = emb @ W_emb^T + b_emb
  gemm_bt<1,0><<<dim3(3072 / 128, 4096 / 128), 256, 0, stream>>>(
      embBF, WihBF, xproj, 4096, 3072, 512, bih, nullptr, nullptr, nullptr);
  gemm_bt<1,0><<<dim3(1024 / 128, 4096 / 128), 256, 0, stream>>>(
      embBF, WembBF, embinf, 4096, 1024, 512, bemb, nullptr, nullptr, nullptr);

  gru_kernel<<<GRU_NWG, 1024, 0, stream>>>(WhhBF, bhh, xproj, h0f, h0bf, hsBF, flags);

  // total = hs @ W_dec^T + ses_inf[b] + emb_inf ; fused pairwise-maxout -> mxBF
  gemm_bt<3,0><<<dim3(1024 / 128, 4096 / 128), 256, 0, stream>>>(
      hsBF, WdecBF, nullptr, 4096, 1024, 1024, nullptr, sesinf, embinf, mxBF);

  // logits = mx @ embed^T  (XCD-swizzled: 8000 WGs % 8 == 0)
  gemm_bt<0,1><<<dim3(32000 / 128, 4096 / 128), 256, 0, stream>>>(
      mxBF, embedBF, out, 4096, 32000, 512, nullptr, nullptr, nullptr, nullptr);
}

// Round 12
// 1158.928 us; speedup vs baseline: 3.1717x; 3.1717x over previous
//
#include <hip/hip_runtime.h>

typedef unsigned short u16;
typedef unsigned int u32;
typedef __attribute__((ext_vector_type(8))) __bf16 bf16x8;
typedef __attribute__((ext_vector_type(4))) float f32x4;
typedef __attribute__((ext_vector_type(4))) u32 u32x4;

#define ASYNC16(g, l) __builtin_amdgcn_global_load_lds( \
    (const __attribute__((address_space(1))) unsigned int*)(g), \
    (__attribute__((address_space(3))) unsigned int*)(l), 16, 0, 0)

__device__ __forceinline__ u16 f2bf(float f){
  unsigned u = __float_as_uint(f);
  unsigned r = u + 0x7fffu + ((u >> 16) & 1u);
  return (u16)(r >> 16);
}

// ---------------- fp32 -> bf16 conversion ----------------
__global__ __launch_bounds__(256) void f2bf_kernel(const float* __restrict__ in,
                                                   u16* __restrict__ out, int n){
  int i = (blockIdx.x * 256 + threadIdx.x) * 8;
  if (i >= n) return;
  float4 a = *(const float4*)&in[i];
  float4 b = *(const float4*)&in[i + 4];
  u16 r[8] = {f2bf(a.x), f2bf(a.y), f2bf(a.z), f2bf(a.w),
              f2bf(b.x), f2bf(b.y), f2bf(b.z), f2bf(b.w)};
  *(uint4*)&out[i] = *(const uint4*)r;
}

// ---------------- ctx projections: ses_inf, h0 ----------------
__global__ __launch_bounds__(256) void ctx_kernel(const float* __restrict__ ctx,
    const float* __restrict__ Wses, const float* __restrict__ Ws2d,
    const float* __restrict__ bs2d, float* __restrict__ sesinf,
    float* __restrict__ h0f, u16* __restrict__ h0bf){
  int id = blockIdx.x * 4 + (threadIdx.x >> 6);
  int lane = threadIdx.x & 63;
  int n = id & 1023, b = (id >> 10) & 15, mat = id >> 14;
  const float* w = (mat ? Ws2d : Wses) + (size_t)n * 1024;
  const float* x = ctx + (size_t)b * 1024;
  float v = 0.f;
  #pragma unroll 4
  for (int k = lane; k < 1024; k += 64) v += x[k] * w[k];
  #pragma unroll
  for (int off = 32; off; off >>= 1) v += __shfl_down(v, off);
  if (lane == 0){
    if (mat == 0) sesinf[b * 1024 + n] = v;
    else {
      float t = tanhf(v + bs2d[n]);
      h0f[b * 1024 + n] = t;
      h0bf[b * 1024 + n] = f2bf(t);
    }
  }
}

// ---------------- embedding gather (bf16 rows) ----------------
__global__ void gather_kernel(const int* __restrict__ target,
                              const u16* __restrict__ embedBF, u16* __restrict__ embBF){
  int i = blockIdx.x;
  int t = target[i];
  int lane = threadIdx.x;
  *(uint4*)&embBF[(size_t)i * 512 + lane * 8] =
      *(const uint4*)&embedBF[(size_t)t * 512 + lane * 8];
}

// ---------------- bf16 GEMM: C[M][N] = A[M][K] * B[N][K]^T (+epilogue) ----------------
// SWZ: bijective XCD-aware wgid remap (requires nwg % 8 == 0)
// EPI: 0=none, 1=+bias[col], 2=+add0+add1 -> C, 3=+add0+add1 -> pairwise-max -> bf16 mxout
template<int EPI, int SWZ>
__global__ __launch_bounds__(256) void gemm_bt(
    const u16* __restrict__ A, const u16* __restrict__ B, float* __restrict__ C,
    int M, int N, int K,
    const float* __restrict__ bias, const float* __restrict__ add0,
    const float* __restrict__ add1, u16* __restrict__ mxout)
{
  __shared__ u16 sA[2][128 * 32];
  __shared__ u16 sB[2][128 * 32];
  int bx = blockIdx.x, by = blockIdx.y;
  if (SWZ){
    int nwg = gridDim.x * gridDim.y;
    int wg = by * gridDim.x + bx;
    int q = nwg >> 3;
    int nw = (wg & 7) * q + (wg >> 3);
    bx = nw % gridDim.x; by = nw / gridDim.x;
  }
  const int n0 = bx * 128;
  const int m0 = by * 128;
  const int tid = threadIdx.x;
  const int lane = tid & 63;
  const int wid = tid >> 6;
  const int wm = (wid >> 1) * 64, wn = (wid & 1) * 64;
  const int l15 = lane & 15, kg = (lane >> 4) * 8;
  (void)M;

  f32x4 zero = {0.f, 0.f, 0.f, 0.f};
  f32x4 acc[4][4];
  #pragma unroll
  for (int m = 0; m < 4; m++)
    #pragma unroll
    for (int n = 0; n < 4; n++) acc[m][n] = zero;

  auto stage = [&](int buf, int kk){
    const u16* Ab = A + (size_t)m0 * K + kk;
    const u16* Bb = B + (size_t)n0 * K + kk;
    #pragma unroll
    for (int j = 0; j < 2; j++){
      int c = j * 256 + tid;
      ASYNC16(Ab + (size_t)(c >> 2) * K + (c & 3) * 8, &sA[buf][c * 8]);
    }
    #pragma unroll
    for (int j = 0; j < 2; j++){
      int c = j * 256 + tid;
      ASYNC16(Bb + (size_t)(c >> 2) * K + (c & 3) * 8, &sB[buf][c * 8]);
    }
  };

  stage(0, 0);
  int cur = 0;
  for (int kk = 0; kk < K; kk += 32){
    __syncthreads();
    if (kk + 32 < K) stage(cur ^ 1, kk + 32);
    bf16x8 af[4], bf_[4];
    #pragma unroll
    for (int m = 0; m < 4; m++)
      af[m] = *(const bf16x8*)&sA[cur][(wm + m * 16 + l15) * 32 + kg];
    #pragma unroll
    for (int n = 0; n < 4; n++)
      bf_[n] = *(const bf16x8*)&sB[cur][(wn + n * 16 + l15) * 32 + kg];
    #pragma unroll
    for (int m = 0; m < 4; m++)
      #pragma unroll
      for (int n = 0; n < 4; n++)
        acc[m][n] = __builtin_amdgcn_mfma_f32_16x16x32_bf16(af[m], bf_[n], acc[m][n], 0, 0, 0);
    cur ^= 1;
  }

  const int rb = m0 + wm + (lane >> 4) * 4;
  const int cb = n0 + wn + l15;
  #pragma unroll
  for (int m = 0; m < 4; m++){
    #pragma unroll
    for (int n = 0; n < 4; n++){
      #pragma unroll
      for (int i = 0; i < 4; i++){
        int row = rb + m * 16 + i;
        int col = cb + n * 16;
        float v = acc[m][n][i];
        if (EPI == 1) v += bias[col];
        if (EPI == 2 || EPI == 3)
          v += add0[(row >> 8) * N + col] + add1[(size_t)row * N + col];
        if (EPI == 3){
          // pairwise maxout: col pairs (2e,2e+1) live in adjacent lanes
          float w = __shfl_xor(v, 1);
          if ((l15 & 1) == 0)
            mxout[(size_t)row * (N >> 1) + (col >> 1)] = f2bf(fmaxf(v, w));
        } else {
          C[(size_t)row * N + col] = v;
        }
      }
    }
  }
}

// ---------------- persistent GRU (R4 protocol, 64 WGs x 1024 thr, 12 MFMA waves) ----------------
// WG g owns hidden cols [g*16, g*16+16); W_hh slice LDS-resident (R11 lesson:
// never stream W / never shrink below 64 WGs). Sync protocol R4-verbatim:
// sc1 write-through publish -> vmcnt(0) drain -> syncthreads -> per-WG flag
// line -> wave0 lane-per-flag poll -> syncthreads; sc1 bulk re-stage.
// NEW vs R10: 16 waves. Wave wid<12 computes K-quarter kq=wid&3 of gate
// wid>>2 (one 16x16 tile, R4's exact LDS pattern on a restricted K range),
// partials in gbuf[12][256]; gates threads (tid<256) sum 4 partials.
// Serial MFMA chain per wave: 32 -> 8. Stage: 1024 thr x 2 loads.
#define GRU_NWG 64
#define GRU_LDS 145408

__global__ __launch_bounds__(1024) void gru_kernel(
    const u16* __restrict__ WhhBF, const float* __restrict__ bhh,
    const float* __restrict__ xproj, const float* __restrict__ h0f,
    const u16* __restrict__ h0bf, u16* __restrict__ hsBF, int* flags)
{
  extern __shared__ char smem[];
  u16*  Wl   = (u16*)smem;                 // [48][1032]
  u16*  hb   = Wl + 48 * 1032;             // [16][1032]
  float* gbuf = (float*)(smem + 132096);   // [12][256]  tile: [batch*16+owncol]
  float* hown = gbuf + 12 * 256;           // [16][16]

  const int g = blockIdx.x;
  const int j0 = g * 16;
  const int tid = threadIdx.x;
  const int lane = tid & 63;
  const int wid = tid >> 6;
  const int l15 = lane & 15, kh8 = (lane >> 4) * 8;

  // one-time: W_hh slice -> LDS (rows {j, H+j, 2H+j})
  for (int c = tid; c < 48 * 128; c += 1024){
    int r = c >> 7, cg = (c & 127) * 8;
    int gate = r >> 4, n = r & 15;
    *(uint4*)&Wl[r * 1032 + cg] =
        *(const uint4*)&WhhBF[(size_t)(gate * 1024 + j0 + n) * 1024 + cg];
  }
  // gates-thread setup (tid < 256): batch bb, own col jj
  const int bb = (tid & 255) >> 4, jj = tid & 15;
  float bh0 = 0.f, bh1 = 0.f, bh2 = 0.f;
  if (tid < 256){
    hown[bb * 16 + jj] = h0f[bb * 1024 + j0 + jj];
    bh0 = bhh[j0 + jj];
    bh1 = bhh[1024 + j0 + jj];
    bh2 = bhh[2048 + j0 + jj];
  }
  u32* hs32 = (u32*)hsBF;
  __syncthreads();

  for (int s = 0; s < 256; ++s){
    // ---- stage h_{s-1} into LDS: 1024 thr x 2 dwordx4 ----
    if (s == 0){
      #pragma unroll
      for (int k = 0; k < 2; k++){
        int c = tid + k * 1024;
        int b = c >> 7, cg = (c & 127) * 8;
        *(uint4*)&hb[b * 1032 + cg] = *(const uint4*)&h0bf[b * 1024 + cg];
      }
    } else {
      u32x4 r[2];
      #pragma unroll
      for (int k = 0; k < 2; k++){
        int c = tid + k * 1024;
        int b = c >> 7, cg = (c & 127) * 8;
        const u16* src = &hsBF[(size_t)((b << 8) + s - 1) * 1024 + cg];
        asm volatile("global_load_dwordx4 %0, %1, off sc1"
                     : "=v"(r[k]) : "v"(src) : "memory");
      }
      asm volatile("s_waitcnt vmcnt(0)" ::: "memory");
      __builtin_amdgcn_sched_barrier(0);   // rule#18 hygiene
      #pragma unroll
      for (int k = 0; k < 2; k++){
        int c = tid + k * 1024;
        int b = c >> 7, cg = (c & 127) * 8;
        *(u32x4*)&hb[b * 1032 + cg] = r[k];
      }
    }

    // prefetch this step's x_proj scalars (gates threads only)
    float xr = 0.f, xz = 0.f, xn = 0.f;
    if (tid < 256){
      const float* xp = xproj + ((size_t)(bb << 8) + s) * 3072;
      xr = xp[j0 + jj]; xz = xp[1024 + j0 + jj]; xn = xp[2048 + j0 + jj];
    }
    __syncthreads();

    // ---- MFMA: wave wid<12 = (gate wid>>2, K-quarter wid&3) ----
    if (wid < 12){
      const int gate = wid >> 2, Koff = (wid & 3) * 256;
      f32x4 acc0 = {0.f, 0.f, 0.f, 0.f};
      f32x4 acc1 = {0.f, 0.f, 0.f, 0.f};
      const u16* wrow = &Wl[(gate * 16 + l15) * 1032 + Koff];
      const u16* hrow = &hb[l15 * 1032 + Koff];
      #pragma unroll
      for (int kk = 0; kk < 256; kk += 64){
        bf16x8 a0 = *(const bf16x8*)&hrow[kk + kh8];
        bf16x8 w0 = *(const bf16x8*)&wrow[kk + kh8];
        acc0 = __builtin_amdgcn_mfma_f32_16x16x32_bf16(a0, w0, acc0, 0, 0, 0);
        bf16x8 a1 = *(const bf16x8*)&hrow[kk + 32 + kh8];
        bf16x8 w1 = *(const bf16x8*)&wrow[kk + 32 + kh8];
        acc1 = __builtin_amdgcn_mfma_f32_16x16x32_bf16(a1, w1, acc1, 0, 0, 0);
      }
      #pragma unroll
      for (int i = 0; i < 4; ++i)
        gbuf[wid * 256 + ((lane >> 4) * 4 + i) * 16 + l15] = acc0[i] + acc1[i];
    }
    __syncthreads();

    // ---- gates (tid<256): sum 4 K-quarter partials per gate; publish ----
    if (tid < 256){
      int ic = bb * 16 + jj;
      float hr = gbuf[0 * 256 + ic] + gbuf[1 * 256 + ic] +
                 gbuf[2 * 256 + ic] + gbuf[3 * 256 + ic] + bh0;
      float hz = gbuf[4 * 256 + ic] + gbuf[5 * 256 + ic] +
                 gbuf[6 * 256 + ic] + gbuf[7 * 256 + ic] + bh1;
      float hn = gbuf[8 * 256 + ic] + gbuf[9 * 256 + ic] +
                 gbuf[10 * 256 + ic] + gbuf[11 * 256 + ic] + bh2;
      float r = 1.f / (1.f + __expf(-(xr + hr)));
      float z = 1.f / (1.f + __expf(-(xz + hz)));
      float nn = tanhf(xn + r * hn);
      float hnew = (1.f - z) * nn + z * hown[bb * 16 + jj];
      hown[bb * 16 + jj] = hnew;
      float hnext = __shfl_down(hnew, 1);
      if ((jj & 1) == 0){
        u32 pack = (u32)f2bf(hnew) | ((u32)f2bf(hnext) << 16);
        size_t e = (size_t)((bb << 8) + s) * 1024 + j0 + jj;
        __hip_atomic_store(&hs32[e >> 1], pack, __ATOMIC_RELAXED,
                           __HIP_MEMORY_SCOPE_AGENT);
      }
    }

    if (s < 255){
      asm volatile("s_waitcnt vmcnt(0)" ::: "memory");
      __syncthreads();
      if (tid == 0)
        __hip_atomic_store(&flags[g * 32], s + 1, __ATOMIC_RELAXED,
                           __HIP_MEMORY_SCOPE_AGENT);
      if (wid == 0){
        while (__hip_atomic_load(&flags[lane * 32], __ATOMIC_RELAXED,
                                 __HIP_MEMORY_SCOPE_AGENT) <= s)
          __builtin_amdgcn_s_sleep(1);
      }
      __syncthreads();
    }
  }
}

extern "C" void kernel_launch(void* const* d_in, const int* in_sizes, int n_in,
                              void* d_out, int out_size, void* d_ws, size_t ws_size,
                              hipStream_t stream)
{
  const float* ctx    = (const float*)d_in[0];
  const int*   target = (const int*)d_in[1];
  const float* embed  = (const float*)d_in[2];
  const float* Ws2d   = (const float*)d_in[3];
  const float* bs2d   = (const float*)d_in[4];
  const float* Wdec   = (const float*)d_in[5];
  const float* Wses   = (const float*)d_in[6];
  const float* Wemb   = (const float*)d_in[7];
  const float* bemb   = (const float*)d_in[8];
  const float* Wih    = (const float*)d_in[9];
  const float* Whh    = (const float*)d_in[10];
  const float* bih    = (const float*)d_in[11];
  const float* bhh    = (const float*)d_in[12];
  float* out = (float*)d_out;

  char* ws = (char*)d_ws;
  size_t off = 0;
  auto alloc = [&](size_t bytes)->char*{
    char* p = ws + off; off += (bytes + 255) & ~(size_t)255; return p;
  };
  u16*   embedBF = (u16*)alloc(32000ull * 512 * 2);
  u16*   WihBF   = (u16*)alloc(3072ull * 512 * 2);
  u16*   WembBF  = (u16*)alloc(1024ull * 512 * 2);
  u16*   WdecBF  = (u16*)alloc(1024ull * 1024 * 2);
  u16*   WhhBF   = (u16*)alloc(3072ull * 1024 * 2);
  u16*   embBF   = (u16*)alloc(4096ull * 512 * 2);
  float* xproj   = (float*)alloc(4096ull * 3072 * 4);
  float* embinf  = (float*)alloc(4096ull * 1024 * 4);
  float* sesinf  = (float*)alloc(16ull * 1024 * 4);
  float* h0f     = (float*)alloc(16ull * 1024 * 4);
  u16*   h0bf    = (u16*)alloc(16ull * 1024 * 2);
  u16*   hsBF    = (u16*)alloc(4096ull * 1024 * 2);
  u16*   mxBF    = (u16*)alloc(4096ull * 512 * 2);
  int*   flags   = (int*)alloc(16384);
  (void)ws_size; (void)in_sizes; (void)n_in; (void)out_size;

  hipFuncSetAttribute((const void*)gru_kernel,
                      hipFuncAttributeMaxDynamicSharedMemorySize, GRU_LDS);
  hipMemsetAsync(flags, 0, 16384, stream);

  auto conv = [&](const float* in, u16* o, size_t n){
    f2bf_kernel<<<dim3((unsigned)((n / 8 + 255) / 256)), 256, 0, stream>>>(in, o, (int)n);
  };
  conv(embed, embedBF, 32000ull * 512);
  conv(Wih,   WihBF,   3072ull * 512);
  conv(Wemb,  WembBF,  1024ull * 512);
  conv(Wdec,  WdecBF,  1024ull * 1024);
  conv(Whh,   WhhBF,   3072ull * 1024);

  ctx_kernel<<<8192, 256, 0, stream>>>(ctx, Wses, Ws2d, bs2d, sesinf, h0f, h0bf);
  gather_kernel<<<4096, 64, 0, stream>>>(target, embedBF, embBF);

  // x_proj = emb @ W_ih^T + b_ih ; emb_inf = emb @ W_emb^T + b_emb
  gemm_bt<1,0><<<dim3(3072 / 128, 4096 / 128), 256, 0, stream>>>(
      embBF, WihBF, xproj, 4096, 3072, 512, bih, nullptr, nullptr, nullptr);
  gemm_bt<1,0><<<dim3(1024 / 128, 4096 / 128), 256, 0, stream>>>(
      embBF, WembBF, embinf, 4096, 1024, 512, bemb, nullptr, nullptr, nullptr);

  gru_kernel<<<GRU_NWG, 1024, GRU_LDS, stream>>>(WhhBF, bhh, xproj, h0f, h0bf, hsBF, flags);

  // total = hs @ W_dec^T + ses_inf[b] + emb_inf ; fused pairwise-maxout -> mxBF
  gemm_bt<3,0><<<dim3(1024 / 128, 4096 / 128), 256, 0, stream>>>(
      hsBF, WdecBF, nullptr, 4096, 1024, 1024, nullptr, sesinf, embinf, mxBF);

  // logits = mx @ embed^T  (XCD-swizzled: 8000 WGs % 8 == 0)
  gemm_bt<0,1><<<dim3(32000 / 128, 4096 / 128), 256, 0, stream>>>(
      mxBF, embedBF, out, 4096, 32000, 512, nullptr, nullptr, nullptr, nullptr);
}